// Round 4
// baseline (2253.137 us; speedup 1.0000x reference)
//
#include <hip/hip_runtime.h>
#include <hip/hip_bf16.h>

typedef __hip_bfloat16 bf16;
typedef __attribute__((ext_vector_type(8))) short short8;
typedef __attribute__((ext_vector_type(4))) float f32x4;

#define NN 20000
#define NE 80000
#define DD 128
#define NITER 15
#define HSTRIDE 136   // 128 + 8 pad: 68 dwords/row -> 2-way LDS aliasing (free)

__device__ inline short f2bs(float f) {
  bf16 h = (bf16)f;
  return *(reinterpret_cast<short*>(&h));
}

// ---------------------------------------------------------------------------
// dtype auto-detect (kept: it provably selected the right path in R3, but
// sample shrunk 256K -> 16K halfwords; 8K samples separate 36% vs 100% sane
// by >50 sigma).  flag = 1 -> bf16 ; flag = 0 -> fp32.
// ---------------------------------------------------------------------------
__global__ void detect_kernel(const unsigned short* __restrict__ p, int nhalf,
                              int* __restrict__ flag) {
  __shared__ int cs[256], ct[256];
  const int t = threadIdx.x;
  int sane = 0, tot = 0;
  for (int i = 2 * t; i < nhalf; i += 512) {
    unsigned short v = p[i];
    int e = (v >> 7) & 0xFF;
    tot++;
    if (v == 0 || (e >= 80 && e <= 170)) sane++;
  }
  cs[t] = sane; ct[t] = tot;
  __syncthreads();
  for (int o = 128; o > 0; o >>= 1) {
    if (t < o) { cs[t] += cs[t + o]; ct[t] += ct[t + o]; }
    __syncthreads();
  }
  if (t == 0) *flag = (cs[0] * 10 > ct[0] * 7) ? 1 : 0;
}

__global__ void in2f_kernel(const void* __restrict__ src, float* __restrict__ dst,
                            int n, const int* __restrict__ flag) {
  int i = blockIdx.x * 256 + threadIdx.x;
  if (i < n) {
    dst[i] = (*flag) ? (float)((const bf16*)src)[i] : ((const float*)src)[i];
  }
}

// W [NITER][K][128] -> Wt [NITER][128][K] bf16
__global__ void w2t_kernel(const void* __restrict__ W, bf16* __restrict__ Wt,
                           int K, const int* __restrict__ flag) {
  int i = blockIdx.x * 256 + threadIdx.x;
  int total = NITER * K * DD;
  if (i < total) {
    float v = (*flag) ? (float)((const bf16*)W)[i] : ((const float*)W)[i];
    int t = i / (K * DD);
    int rem = i - t * K * DD;
    int k = rem >> 7;
    int n = rem & 127;
    Wt[(size_t)t * K * DD + (size_t)n * K + k] = (bf16)v;
  }
}

__global__ void outw_kernel(const float* __restrict__ xf, const float* __restrict__ ef,
                            void* __restrict__ out, const int* __restrict__ flag) {
  int i = blockIdx.x * 256 + threadIdx.x;
  const int nx = NN * DD, total = (NN + NE) * DD;
  if (i < total) {
    float v = (i < nx) ? xf[i] : ef[i - nx];
    if (*flag) ((bf16*)out)[i] = (bf16)v;
    else       ((float*)out)[i] = v;
  }
}

// ---------------------------------------------------------------------------
// Fully fused 3-layer MLP (Linear-ReLU-Linear-ReLU-Linear-LayerNorm+residual).
// One 128-row tile per block, 4 waves, 16x16x32 bf16 MFMA, fp32 accumulate.
// A/B fragments load DIRECTLY global->registers (barrier-free K-loops); the
// inter-layer activations round-trip through padded LDS (C-layout -> A-layout
// transform). Residual state fp32 in stf.
// AMODE 1: A0 = concat(xf[row[m]], xf[col[m]], ef[m])  (K0=384)
// AMODE 2: A0 = concat(xf[m], aggf[m])                 (K0=256)
// ---------------------------------------------------------------------------
template<int K0, int AMODE>
__global__ __launch_bounds__(256) void fused_mlp(
    const float* __restrict__ S0,
    const float* __restrict__ S1,
    const int*   __restrict__ eidx,
    const bf16*  __restrict__ W0t,   // [128][K0]
    const bf16*  __restrict__ W1t,   // [128][128]
    const bf16*  __restrict__ W2t,   // [128][128]
    const float* __restrict__ b0,
    const float* __restrict__ b1,
    const float* __restrict__ b2,
    const float* __restrict__ gamma,
    const float* __restrict__ beta,
    float*       __restrict__ stf,   // fp32 residual state (in/out)
    int M)
{
  __shared__ __align__(16) bf16 Hls[128 * HSTRIDE];
  __shared__ float redS[2][128];
  __shared__ float redQ[2][128];
  __shared__ float mrow[128][2];

  const int tid  = threadIdx.x;
  const int lane = tid & 63;
  const int wv   = tid >> 6;
  const int wm   = wv >> 1, wn = wv & 1;
  const int l15  = lane & 15, quad = lane >> 4;
  const int m0   = blockIdx.x * 128;

  // rows this lane owns for A-fragments (4 per lane) + gather indices
  int rowm[4], ir[4], ic[4];
#pragma unroll
  for (int mi = 0; mi < 4; mi++) {
    rowm[mi] = min(m0 + wm * 64 + mi * 16 + l15, M - 1);
    if (AMODE == 1) { ir[mi] = eidx[rowm[mi]]; ic[mi] = eidx[NE + rowm[mi]]; }
  }

  f32x4 acc[4][4];
#pragma unroll
  for (int i = 0; i < 4; i++)
#pragma unroll
    for (int j = 0; j < 4; j++) acc[i][j] = (f32x4){0.f, 0.f, 0.f, 0.f};

  // ---------------- Phase 1: H0 = relu(A0 @ W0 + b0) ----------------
  const int nst = K0 / 32;
#pragma unroll
  for (int s = 0; s < nst; s++) {
    const int kk = s * 32;
    short8 af[4];
#pragma unroll
    for (int mi = 0; mi < 4; mi++) {
      const int ks = (kk & 127) + quad * 8;
      const float* p;
      if (AMODE == 1) {
        const int seg = kk >> 7;
        const float* base = (seg == 0) ? (S0 + (size_t)ir[mi] * DD)
                          : (seg == 1) ? (S0 + (size_t)ic[mi] * DD)
                                       : (S1 + (size_t)rowm[mi] * DD);
        p = base + ks;
      } else {
        const float* base = (kk >> 7) ? (S1 + (size_t)rowm[mi] * DD)
                                      : (S0 + (size_t)rowm[mi] * DD);
        p = base + ks;
      }
      f32x4 u0 = *(const f32x4*)p;
      f32x4 u1 = *(const f32x4*)(p + 4);
      short8 a;
#pragma unroll
      for (int j = 0; j < 4; j++) { a[j] = f2bs(u0[j]); a[j + 4] = f2bs(u1[j]); }
      af[mi] = a;
    }
    short8 bfr[4];
#pragma unroll
    for (int ni = 0; ni < 4; ni++)
      bfr[ni] = *(const short8*)(W0t + (size_t)(wn * 64 + ni * 16 + l15) * K0 + kk + quad * 8);
#pragma unroll
    for (int mi = 0; mi < 4; mi++)
#pragma unroll
      for (int ni = 0; ni < 4; ni++)
        acc[mi][ni] = __builtin_amdgcn_mfma_f32_16x16x32_bf16(af[mi], bfr[ni], acc[mi][ni], 0, 0, 0);
  }

  {
    float bv[4];
#pragma unroll
    for (int ni = 0; ni < 4; ni++) bv[ni] = b0[wn * 64 + ni * 16 + l15];
#pragma unroll
    for (int mi = 0; mi < 4; mi++)
#pragma unroll
      for (int r = 0; r < 4; r++) {
        const int row = wm * 64 + mi * 16 + quad * 4 + r;
#pragma unroll
        for (int ni = 0; ni < 4; ni++) {
          const int col = wn * 64 + ni * 16 + l15;
          Hls[row * HSTRIDE + col] = (bf16)fmaxf(acc[mi][ni][r] + bv[ni], 0.f);
        }
      }
  }
  __syncthreads();

  // ---------------- Phase 2: H1 = relu(H0 @ W1 + b1) ----------------
#pragma unroll
  for (int i = 0; i < 4; i++)
#pragma unroll
    for (int j = 0; j < 4; j++) acc[i][j] = (f32x4){0.f, 0.f, 0.f, 0.f};
#pragma unroll
  for (int s = 0; s < 4; s++) {
    const int kk = s * 32;
    short8 af[4], bfr[4];
#pragma unroll
    for (int mi = 0; mi < 4; mi++)
      af[mi] = *(const short8*)&Hls[(wm * 64 + mi * 16 + l15) * HSTRIDE + kk + quad * 8];
#pragma unroll
    for (int ni = 0; ni < 4; ni++)
      bfr[ni] = *(const short8*)(W1t + (size_t)(wn * 64 + ni * 16 + l15) * 128 + kk + quad * 8);
#pragma unroll
    for (int mi = 0; mi < 4; mi++)
#pragma unroll
      for (int ni = 0; ni < 4; ni++)
        acc[mi][ni] = __builtin_amdgcn_mfma_f32_16x16x32_bf16(af[mi], bfr[ni], acc[mi][ni], 0, 0, 0);
  }
  __syncthreads();   // all H0 reads complete before overwrite
  {
    float bv[4];
#pragma unroll
    for (int ni = 0; ni < 4; ni++) bv[ni] = b1[wn * 64 + ni * 16 + l15];
#pragma unroll
    for (int mi = 0; mi < 4; mi++)
#pragma unroll
      for (int r = 0; r < 4; r++) {
        const int row = wm * 64 + mi * 16 + quad * 4 + r;
#pragma unroll
        for (int ni = 0; ni < 4; ni++) {
          const int col = wn * 64 + ni * 16 + l15;
          Hls[row * HSTRIDE + col] = (bf16)fmaxf(acc[mi][ni][r] + bv[ni], 0.f);
        }
      }
  }
  __syncthreads();

  // ---------------- Phase 3: Y = H1 @ W2 + b2 ; LN ; residual ----------------
#pragma unroll
  for (int i = 0; i < 4; i++)
#pragma unroll
    for (int j = 0; j < 4; j++) acc[i][j] = (f32x4){0.f, 0.f, 0.f, 0.f};
#pragma unroll
  for (int s = 0; s < 4; s++) {
    const int kk = s * 32;
    short8 af[4], bfr[4];
#pragma unroll
    for (int mi = 0; mi < 4; mi++)
      af[mi] = *(const short8*)&Hls[(wm * 64 + mi * 16 + l15) * HSTRIDE + kk + quad * 8];
#pragma unroll
    for (int ni = 0; ni < 4; ni++)
      bfr[ni] = *(const short8*)(W2t + (size_t)(wn * 64 + ni * 16 + l15) * 128 + kk + quad * 8);
#pragma unroll
    for (int mi = 0; mi < 4; mi++)
#pragma unroll
      for (int ni = 0; ni < 4; ni++)
        acc[mi][ni] = __builtin_amdgcn_mfma_f32_16x16x32_bf16(af[mi], bfr[ni], acc[mi][ni], 0, 0, 0);
  }

  float bv[4], gv[4], btv[4];
#pragma unroll
  for (int ni = 0; ni < 4; ni++) {
    const int col = wn * 64 + ni * 16 + l15;
    bv[ni] = b2[col]; gv[ni] = gamma[col]; btv[ni] = beta[col];
  }

  float s1v[4][4], s2v[4][4];
#pragma unroll
  for (int mi = 0; mi < 4; mi++)
#pragma unroll
    for (int r = 0; r < 4; r++) {
      float a = 0.f, b = 0.f;
#pragma unroll
      for (int ni = 0; ni < 4; ni++) {
        const float v = acc[mi][ni][r] + bv[ni];
        a += v; b += v * v;
      }
      s1v[mi][r] = a; s2v[mi][r] = b;
    }
#pragma unroll
  for (int off = 1; off < 16; off <<= 1) {
#pragma unroll
    for (int mi = 0; mi < 4; mi++)
#pragma unroll
      for (int r = 0; r < 4; r++) {
        s1v[mi][r] += __shfl_xor(s1v[mi][r], off);
        s2v[mi][r] += __shfl_xor(s2v[mi][r], off);
      }
  }
  if (l15 == 0) {
#pragma unroll
    for (int mi = 0; mi < 4; mi++)
#pragma unroll
      for (int r = 0; r < 4; r++) {
        const int rl = wm * 64 + mi * 16 + quad * 4 + r;
        redS[wn][rl] = s1v[mi][r];
        redQ[wn][rl] = s2v[mi][r];
      }
  }
  __syncthreads();
  if (tid < 128) {
    const float t1 = redS[0][tid] + redS[1][tid];
    const float t2 = redQ[0][tid] + redQ[1][tid];
    const float mu = t1 * (1.0f / 128.0f);
    const float var = fmaxf(t2 * (1.0f / 128.0f) - mu * mu, 0.0f);
    mrow[tid][0] = mu;
    mrow[tid][1] = rsqrtf(var + 1e-5f);
  }
  __syncthreads();
#pragma unroll
  for (int mi = 0; mi < 4; mi++)
#pragma unroll
    for (int r = 0; r < 4; r++) {
      const int rl = wm * 64 + mi * 16 + quad * 4 + r;
      const int m = m0 + rl;
      if (m < M) {
        const float mu = mrow[rl][0], rs = mrow[rl][1];
#pragma unroll
        for (int ni = 0; ni < 4; ni++) {
          const int col = wn * 64 + ni * 16 + l15;
          const float v = acc[mi][ni][r] + bv[ni];
          const float lnv = (v - mu) * rs * gv[ni] + btv[ni];
          const size_t idx = (size_t)m * DD + col;
          stf[idx] = lnv + stf[idx];
        }
      }
    }
}

// --------------------------- CSR build + aggregate -------------------------
__global__ void zero_kernel(int* __restrict__ p, int n) {
  int i = blockIdx.x * 256 + threadIdx.x;
  if (i < n) p[i] = 0;
}

__global__ void hist_kernel(const int* __restrict__ eidx, int* __restrict__ counts) {
  int e = blockIdx.x * 256 + threadIdx.x;
  if (e < NE) atomicAdd(&counts[eidx[NE + e]], 1);
}

__global__ void scan_kernel(const int* __restrict__ counts, int* __restrict__ offs,
                            int* __restrict__ cursor) {
  __shared__ int sums[1024];
  const int t = threadIdx.x;
  const int base = t * 20;
  int local[20];
  int s = 0;
  for (int i = 0; i < 20; i++) {
    int idx = base + i;
    int c = (idx < NN) ? counts[idx] : 0;
    local[i] = s; s += c;
  }
  sums[t] = s;
  __syncthreads();
  for (int off = 1; off < 1024; off <<= 1) {
    int v = 0;
    if (t >= off) v = sums[t - off];
    __syncthreads();
    if (t >= off) sums[t] += v;
    __syncthreads();
  }
  int excl = (t == 0) ? 0 : sums[t - 1];
  for (int i = 0; i < 20; i++) {
    int idx = base + i;
    if (idx < NN) { offs[idx] = excl + local[i]; cursor[idx] = 0; }
  }
  if (t == 1023) offs[NN] = sums[1023];
}

__global__ void fill_kernel(const int* __restrict__ eidx, const int* __restrict__ offs,
                            int* __restrict__ cursor, int* __restrict__ sorted) {
  int e = blockIdx.x * 256 + threadIdx.x;
  if (e < NE) {
    int n = eidx[NE + e];
    int p = atomicAdd(&cursor[n], 1);
    sorted[offs[n] + p] = e;
  }
}

__global__ void aggregate_kernel(const float* __restrict__ ef, const int* __restrict__ offs,
                                 const int* __restrict__ sorted, float* __restrict__ aggf) {
  const int node = blockIdx.x * 4 + (threadIdx.x >> 6);
  const int lane = threadIdx.x & 63;
  if (node >= NN) return;
  const int s = offs[node], t = offs[node + 1];
  float a0 = 0.f, a1 = 0.f;
  for (int i = s; i < t; i++) {
    const int e = sorted[i];
    a0 += ef[(size_t)e * DD + lane];
    a1 += ef[(size_t)e * DD + 64 + lane];
  }
  aggf[(size_t)node * DD + lane]      = a0;
  aggf[(size_t)node * DD + 64 + lane] = a1;
}

// ---------------------------------------------------------------------------
extern "C" void kernel_launch(void* const* d_in, const int* in_sizes, int n_in,
                              void* d_out, int out_size, void* d_ws, size_t ws_size,
                              hipStream_t stream) {
  const void* x_in = d_in[0];
  const void* e_in = d_in[1];
  const void* eW0 = d_in[2];
  const void* eB0 = d_in[3];
  const void* eW1 = d_in[4];
  const void* eB1 = d_in[5];
  const void* eW2 = d_in[6];
  const void* eB2 = d_in[7];
  const void* eG  = d_in[8];
  const void* eBt = d_in[9];
  const void* nW0 = d_in[10];
  const void* nB0 = d_in[11];
  const void* nW1 = d_in[12];
  const void* nB1 = d_in[13];
  const void* nW2 = d_in[14];
  const void* nB2 = d_in[15];
  const void* nG  = d_in[16];
  const void* nBt = d_in[17];
  const int*  eidx = (const int*)d_in[18];

  char* ws = (char*)d_ws;
  size_t off = 0;
  auto alloc = [&](size_t bytes) -> char* {
    char* p = ws + off;
    off = (off + bytes + 255) & ~(size_t)255;
    return p;
  };

  float* xf   = (float*)alloc((size_t)NN * DD * 4);
  float* ef   = (float*)alloc((size_t)NE * DD * 4);
  float* aggf = (float*)alloc((size_t)NN * DD * 4);
  bf16*  eW0t = (bf16*)alloc((size_t)NITER * 384 * DD * 2);
  bf16*  eW1t = (bf16*)alloc((size_t)NITER * 128 * DD * 2);
  bf16*  eW2t = (bf16*)alloc((size_t)NITER * 128 * DD * 2);
  bf16*  nW0t = (bf16*)alloc((size_t)NITER * 256 * DD * 2);
  bf16*  nW1t = (bf16*)alloc((size_t)NITER * 128 * DD * 2);
  bf16*  nW2t = (bf16*)alloc((size_t)NITER * 128 * DD * 2);
  const int NB = NITER * DD;
  float* eB0f = (float*)alloc(NB * 4);
  float* eB1f = (float*)alloc(NB * 4);
  float* eB2f = (float*)alloc(NB * 4);
  float* eGf  = (float*)alloc(NB * 4);
  float* eBtf = (float*)alloc(NB * 4);
  float* nB0f = (float*)alloc(NB * 4);
  float* nB1f = (float*)alloc(NB * 4);
  float* nB2f = (float*)alloc(NB * 4);
  float* nGf  = (float*)alloc(NB * 4);
  float* nBtf = (float*)alloc(NB * 4);
  int* counts = (int*)alloc((size_t)NN * 4);
  int* cursor = (int*)alloc((size_t)NN * 4);
  int* offs   = (int*)alloc((size_t)(NN + 1) * 4);
  int* sorted = (int*)alloc((size_t)NE * 4);
  int* flag   = (int*)alloc(4);

  detect_kernel<<<1, 256, 0, stream>>>((const unsigned short*)x_in, 16384, flag);

  in2f_kernel<<<(NN * DD + 255) / 256, 256, 0, stream>>>(x_in, xf, NN * DD, flag);
  in2f_kernel<<<(NE * DD + 255) / 256, 256, 0, stream>>>(e_in, ef, NE * DD, flag);
  w2t_kernel<<<(NITER * 384 * DD + 255) / 256, 256, 0, stream>>>(eW0, eW0t, 384, flag);
  w2t_kernel<<<(NITER * 128 * DD + 255) / 256, 256, 0, stream>>>(eW1, eW1t, 128, flag);
  w2t_kernel<<<(NITER * 128 * DD + 255) / 256, 256, 0, stream>>>(eW2, eW2t, 128, flag);
  w2t_kernel<<<(NITER * 256 * DD + 255) / 256, 256, 0, stream>>>(nW0, nW0t, 256, flag);
  w2t_kernel<<<(NITER * 128 * DD + 255) / 256, 256, 0, stream>>>(nW1, nW1t, 128, flag);
  w2t_kernel<<<(NITER * 128 * DD + 255) / 256, 256, 0, stream>>>(nW2, nW2t, 128, flag);
  in2f_kernel<<<(NB + 255) / 256, 256, 0, stream>>>(eB0, eB0f, NB, flag);
  in2f_kernel<<<(NB + 255) / 256, 256, 0, stream>>>(eB1, eB1f, NB, flag);
  in2f_kernel<<<(NB + 255) / 256, 256, 0, stream>>>(eB2, eB2f, NB, flag);
  in2f_kernel<<<(NB + 255) / 256, 256, 0, stream>>>(eG,  eGf,  NB, flag);
  in2f_kernel<<<(NB + 255) / 256, 256, 0, stream>>>(eBt, eBtf, NB, flag);
  in2f_kernel<<<(NB + 255) / 256, 256, 0, stream>>>(nB0, nB0f, NB, flag);
  in2f_kernel<<<(NB + 255) / 256, 256, 0, stream>>>(nB1, nB1f, NB, flag);
  in2f_kernel<<<(NB + 255) / 256, 256, 0, stream>>>(nB2, nB2f, NB, flag);
  in2f_kernel<<<(NB + 255) / 256, 256, 0, stream>>>(nG,  nGf,  NB, flag);
  in2f_kernel<<<(NB + 255) / 256, 256, 0, stream>>>(nBt, nBtf, NB, flag);

  zero_kernel<<<(NN + 255) / 256, 256, 0, stream>>>(counts, NN);
  hist_kernel<<<(NE + 255) / 256, 256, 0, stream>>>(eidx, counts);
  scan_kernel<<<1, 1024, 0, stream>>>(counts, offs, cursor);
  fill_kernel<<<(NE + 255) / 256, 256, 0, stream>>>(eidx, offs, cursor, sorted);

  const int egrid = NE / 128;               // 625
  const int ngrid = (NN + 127) / 128;       // 157

  for (int t = 0; t < NITER; t++) {
    fused_mlp<384, 1><<<egrid, 256, 0, stream>>>(
        xf, ef, eidx,
        eW0t + (size_t)t * 384 * DD, eW1t + (size_t)t * 128 * DD, eW2t + (size_t)t * 128 * DD,
        eB0f + t * DD, eB1f + t * DD, eB2f + t * DD,
        eGf + t * DD, eBtf + t * DD, ef, NE);
    aggregate_kernel<<<(NN + 3) / 4, 256, 0, stream>>>(ef, offs, sorted, aggf);
    fused_mlp<256, 2><<<ngrid, 256, 0, stream>>>(
        xf, aggf, nullptr,
        nW0t + (size_t)t * 256 * DD, nW1t + (size_t)t * 128 * DD, nW2t + (size_t)t * 128 * DD,
        nB0f + t * DD, nB1f + t * DD, nB2f + t * DD,
        nGf + t * DD, nBtf + t * DD, xf, NN);
  }

  outw_kernel<<<((NN + NE) * DD + 255) / 256, 256, 0, stream>>>(xf, ef, d_out, flag);
}

// Round 5
// 1963.233 us; speedup vs baseline: 1.1477x; 1.1477x over previous
//
#include <hip/hip_runtime.h>
#include <hip/hip_bf16.h>

typedef __hip_bfloat16 bf16;
typedef __attribute__((ext_vector_type(8))) short short8;
typedef __attribute__((ext_vector_type(4))) float f32x4;

#define NN 20000
#define NE 80000
#define DD 128
#define NITER 15
#define HSTRIDE 136   // 64-row tile: row stride 272 B -> 2-way LDS aliasing (free, m136)

// ---------------------------------------------------------------------------
// dtype auto-detect. flag = 1 -> bf16 ; flag = 0 -> fp32.
// ---------------------------------------------------------------------------
__global__ void detect_kernel(const unsigned short* __restrict__ p, int nhalf,
                              int* __restrict__ flag) {
  __shared__ int cs[256], ct[256];
  const int t = threadIdx.x;
  int sane = 0, tot = 0;
  for (int i = 2 * t; i < nhalf; i += 512) {
    unsigned short v = p[i];
    int e = (v >> 7) & 0xFF;
    tot++;
    if (v == 0 || (e >= 80 && e <= 170)) sane++;
  }
  cs[t] = sane; ct[t] = tot;
  __syncthreads();
  for (int o = 128; o > 0; o >>= 1) {
    if (t < o) { cs[t] += cs[t + o]; ct[t] += ct[t + o]; }
    __syncthreads();
  }
  if (t == 0) *flag = (cs[0] * 10 > ct[0] * 7) ? 1 : 0;
}

// src -> fp32 state + bf16 mirror
__global__ void in2fb_kernel(const void* __restrict__ src, float* __restrict__ dstf,
                             bf16* __restrict__ dstb, int n, const int* __restrict__ flag) {
  int i = blockIdx.x * 256 + threadIdx.x;
  if (i < n) {
    float v = (*flag) ? (float)((const bf16*)src)[i] : ((const float*)src)[i];
    dstf[i] = v;
    dstb[i] = (bf16)v;
  }
}

__global__ void in2f_kernel(const void* __restrict__ src, float* __restrict__ dst,
                            int n, const int* __restrict__ flag) {
  int i = blockIdx.x * 256 + threadIdx.x;
  if (i < n) {
    dst[i] = (*flag) ? (float)((const bf16*)src)[i] : ((const float*)src)[i];
  }
}

// W [NITER][K][128] -> Wt [NITER][128][K] bf16
__global__ void w2t_kernel(const void* __restrict__ W, bf16* __restrict__ Wt,
                           int K, const int* __restrict__ flag) {
  int i = blockIdx.x * 256 + threadIdx.x;
  int total = NITER * K * DD;
  if (i < total) {
    float v = (*flag) ? (float)((const bf16*)W)[i] : ((const float*)W)[i];
    int t = i / (K * DD);
    int rem = i - t * K * DD;
    int k = rem >> 7;
    int n = rem & 127;
    Wt[(size_t)t * K * DD + (size_t)n * K + k] = (bf16)v;
  }
}

__global__ void outw_kernel(const float* __restrict__ xf, const float* __restrict__ ef,
                            void* __restrict__ out, const int* __restrict__ flag) {
  int i = blockIdx.x * 256 + threadIdx.x;
  const int nx = NN * DD, total = (NN + NE) * DD;
  if (i < total) {
    float v = (i < nx) ? xf[i] : ef[i - nx];
    if (*flag) ((bf16*)out)[i] = (bf16)v;
    else       ((float*)out)[i] = v;
  }
}

// ---------------------------------------------------------------------------
// Fused 3-layer MLP, 64-row x 128-col tile, 4 waves (wave = 32 rows x 64 cols,
// 2x4 16x16x32 MFMA tiles, 32 acc VGPRs). A/B fragments load directly
// global->registers from bf16 mirrors; inter-layer H via padded LDS.
// Residual state fp32 (stf) + bf16 mirror (stb) written in epilogue.
// AMODE 1: A0 = concat(xb[row[m]], xb[col[m]], eb[m])  (K0=384)
// AMODE 2: A0 = concat(xb[m], aggb[m])                 (K0=256)
// ---------------------------------------------------------------------------
template<int K0, int AMODE>
__global__ __launch_bounds__(256, 4) void fused_mlp(
    const bf16*  __restrict__ S0b,
    const bf16*  __restrict__ S1b,
    const int*   __restrict__ eidx,
    const bf16*  __restrict__ W0t,   // [128][K0]
    const bf16*  __restrict__ W1t,   // [128][128]
    const bf16*  __restrict__ W2t,   // [128][128]
    const float* __restrict__ b0,
    const float* __restrict__ b1,
    const float* __restrict__ b2,
    const float* __restrict__ gamma,
    const float* __restrict__ beta,
    float*       __restrict__ stf,   // fp32 residual state (in/out)
    bf16*        __restrict__ stb,   // bf16 mirror (out)
    int M)
{
  __shared__ __align__(16) bf16 Hls[64 * HSTRIDE];
  __shared__ float redS[2][64];
  __shared__ float redQ[2][64];
  __shared__ float mrow[64][2];

  const int tid  = threadIdx.x;
  const int lane = tid & 63;
  const int wv   = tid >> 6;
  const int wm   = wv >> 1, wn = wv & 1;       // wave: rows wm*32.., cols wn*64..
  const int l15  = lane & 15, quad = lane >> 4;
  const int m0   = blockIdx.x * 64;

  int rowm[2], ir[2], ic[2];
#pragma unroll
  for (int mi = 0; mi < 2; mi++) {
    rowm[mi] = min(m0 + wm * 32 + mi * 16 + l15, M - 1);
    if (AMODE == 1) { ir[mi] = eidx[rowm[mi]]; ic[mi] = eidx[NE + rowm[mi]]; }
  }

  f32x4 acc[2][4];
#pragma unroll
  for (int i = 0; i < 2; i++)
#pragma unroll
    for (int j = 0; j < 4; j++) acc[i][j] = (f32x4){0.f, 0.f, 0.f, 0.f};

  // ---------------- Phase 1: H0 = relu(A0 @ W0 + b0) ----------------
#pragma unroll
  for (int s = 0; s < K0 / 32; s++) {
    const int kk = s * 32;
    const int ks = (kk & 127) + quad * 8;
    short8 af[2];
#pragma unroll
    for (int mi = 0; mi < 2; mi++) {
      const bf16* base;
      if (AMODE == 1) {
        const int seg = kk >> 7;
        base = (seg == 0) ? S0b + (size_t)ir[mi] * DD
             : (seg == 1) ? S0b + (size_t)ic[mi] * DD
                          : S1b + (size_t)rowm[mi] * DD;
      } else {
        base = (kk >> 7) ? S1b + (size_t)rowm[mi] * DD
                         : S0b + (size_t)rowm[mi] * DD;
      }
      af[mi] = *(const short8*)(base + ks);
    }
    short8 bfr[4];
#pragma unroll
    for (int ni = 0; ni < 4; ni++)
      bfr[ni] = *(const short8*)(W0t + (size_t)(wn * 64 + ni * 16 + l15) * K0 + kk + quad * 8);
#pragma unroll
    for (int mi = 0; mi < 2; mi++)
#pragma unroll
      for (int ni = 0; ni < 4; ni++)
        acc[mi][ni] = __builtin_amdgcn_mfma_f32_16x16x32_bf16(af[mi], bfr[ni], acc[mi][ni], 0, 0, 0);
  }

  {
    float bv[4];
#pragma unroll
    for (int ni = 0; ni < 4; ni++) bv[ni] = b0[wn * 64 + ni * 16 + l15];
#pragma unroll
    for (int mi = 0; mi < 2; mi++)
#pragma unroll
      for (int r = 0; r < 4; r++) {
        const int row = wm * 32 + mi * 16 + quad * 4 + r;
#pragma unroll
        for (int ni = 0; ni < 4; ni++) {
          const int col = wn * 64 + ni * 16 + l15;
          Hls[row * HSTRIDE + col] = (bf16)fmaxf(acc[mi][ni][r] + bv[ni], 0.f);
        }
      }
  }
  __syncthreads();

  // ---------------- Phase 2: H1 = relu(H0 @ W1 + b1) ----------------
#pragma unroll
  for (int i = 0; i < 2; i++)
#pragma unroll
    for (int j = 0; j < 4; j++) acc[i][j] = (f32x4){0.f, 0.f, 0.f, 0.f};
#pragma unroll
  for (int s = 0; s < 4; s++) {
    const int kk = s * 32;
    short8 af[2], bfr[4];
#pragma unroll
    for (int mi = 0; mi < 2; mi++)
      af[mi] = *(const short8*)&Hls[(wm * 32 + mi * 16 + l15) * HSTRIDE + kk + quad * 8];
#pragma unroll
    for (int ni = 0; ni < 4; ni++)
      bfr[ni] = *(const short8*)(W1t + (size_t)(wn * 64 + ni * 16 + l15) * 128 + kk + quad * 8);
#pragma unroll
    for (int mi = 0; mi < 2; mi++)
#pragma unroll
      for (int ni = 0; ni < 4; ni++)
        acc[mi][ni] = __builtin_amdgcn_mfma_f32_16x16x32_bf16(af[mi], bfr[ni], acc[mi][ni], 0, 0, 0);
  }
  __syncthreads();
  {
    float bv[4];
#pragma unroll
    for (int ni = 0; ni < 4; ni++) bv[ni] = b1[wn * 64 + ni * 16 + l15];
#pragma unroll
    for (int mi = 0; mi < 2; mi++)
#pragma unroll
      for (int r = 0; r < 4; r++) {
        const int row = wm * 32 + mi * 16 + quad * 4 + r;
#pragma unroll
        for (int ni = 0; ni < 4; ni++) {
          const int col = wn * 64 + ni * 16 + l15;
          Hls[row * HSTRIDE + col] = (bf16)fmaxf(acc[mi][ni][r] + bv[ni], 0.f);
        }
      }
  }
  __syncthreads();

  // ---------------- Phase 3: Y = H1 @ W2 + b2 ; LN ; residual ----------------
#pragma unroll
  for (int i = 0; i < 2; i++)
#pragma unroll
    for (int j = 0; j < 4; j++) acc[i][j] = (f32x4){0.f, 0.f, 0.f, 0.f};
#pragma unroll
  for (int s = 0; s < 4; s++) {
    const int kk = s * 32;
    short8 af[2], bfr[4];
#pragma unroll
    for (int mi = 0; mi < 2; mi++)
      af[mi] = *(const short8*)&Hls[(wm * 32 + mi * 16 + l15) * HSTRIDE + kk + quad * 8];
#pragma unroll
    for (int ni = 0; ni < 4; ni++)
      bfr[ni] = *(const short8*)(W2t + (size_t)(wn * 64 + ni * 16 + l15) * 128 + kk + quad * 8);
#pragma unroll
    for (int mi = 0; mi < 2; mi++)
#pragma unroll
      for (int ni = 0; ni < 4; ni++)
        acc[mi][ni] = __builtin_amdgcn_mfma_f32_16x16x32_bf16(af[mi], bfr[ni], acc[mi][ni], 0, 0, 0);
  }

  float bv[4], gv[4], btv[4];
#pragma unroll
  for (int ni = 0; ni < 4; ni++) {
    const int col = wn * 64 + ni * 16 + l15;
    bv[ni] = b2[col]; gv[ni] = gamma[col]; btv[ni] = beta[col];
  }

  float s1v[2][4], s2v[2][4];
#pragma unroll
  for (int mi = 0; mi < 2; mi++)
#pragma unroll
    for (int r = 0; r < 4; r++) {
      float a = 0.f, b = 0.f;
#pragma unroll
      for (int ni = 0; ni < 4; ni++) {
        const float v = acc[mi][ni][r] + bv[ni];
        a += v; b += v * v;
      }
      s1v[mi][r] = a; s2v[mi][r] = b;
    }
#pragma unroll
  for (int off = 1; off < 16; off <<= 1) {
#pragma unroll
    for (int mi = 0; mi < 2; mi++)
#pragma unroll
      for (int r = 0; r < 4; r++) {
        s1v[mi][r] += __shfl_xor(s1v[mi][r], off);
        s2v[mi][r] += __shfl_xor(s2v[mi][r], off);
      }
  }
  if (l15 == 0) {
#pragma unroll
    for (int mi = 0; mi < 2; mi++)
#pragma unroll
      for (int r = 0; r < 4; r++) {
        const int rl = wm * 32 + mi * 16 + quad * 4 + r;
        redS[wn][rl] = s1v[mi][r];
        redQ[wn][rl] = s2v[mi][r];
      }
  }
  __syncthreads();
  if (tid < 64) {
    const float t1 = redS[0][tid] + redS[1][tid];
    const float t2 = redQ[0][tid] + redQ[1][tid];
    const float mu = t1 * (1.0f / 128.0f);
    const float var = fmaxf(t2 * (1.0f / 128.0f) - mu * mu, 0.0f);
    mrow[tid][0] = mu;
    mrow[tid][1] = rsqrtf(var + 1e-5f);
  }
  __syncthreads();
#pragma unroll
  for (int mi = 0; mi < 2; mi++)
#pragma unroll
    for (int r = 0; r < 4; r++) {
      const int rl = wm * 32 + mi * 16 + quad * 4 + r;
      const int m = m0 + rl;
      if (m < M) {
        const float mu = mrow[rl][0], rs = mrow[rl][1];
#pragma unroll
        for (int ni = 0; ni < 4; ni++) {
          const int col = wn * 64 + ni * 16 + l15;
          const float v = acc[mi][ni][r] + bv[ni];
          const float lnv = (v - mu) * rs * gv[ni] + btv[ni];
          const size_t idx = (size_t)m * DD + col;
          const float nv = lnv + stf[idx];
          stf[idx] = nv;
          stb[idx] = (bf16)nv;
        }
      }
    }
}

// --------------------------- CSR build + aggregate -------------------------
__global__ void zero_kernel(int* __restrict__ p, int n) {
  int i = blockIdx.x * 256 + threadIdx.x;
  if (i < n) p[i] = 0;
}

__global__ void hist_kernel(const int* __restrict__ eidx, int* __restrict__ counts) {
  int e = blockIdx.x * 256 + threadIdx.x;
  if (e < NE) atomicAdd(&counts[eidx[NE + e]], 1);
}

__global__ void scan_kernel(const int* __restrict__ counts, int* __restrict__ offs,
                            int* __restrict__ cursor) {
  __shared__ int sums[1024];
  const int t = threadIdx.x;
  const int base = t * 20;
  int local[20];
  int s = 0;
  for (int i = 0; i < 20; i++) {
    int idx = base + i;
    int c = (idx < NN) ? counts[idx] : 0;
    local[i] = s; s += c;
  }
  sums[t] = s;
  __syncthreads();
  for (int off = 1; off < 1024; off <<= 1) {
    int v = 0;
    if (t >= off) v = sums[t - off];
    __syncthreads();
    if (t >= off) sums[t] += v;
    __syncthreads();
  }
  int excl = (t == 0) ? 0 : sums[t - 1];
  for (int i = 0; i < 20; i++) {
    int idx = base + i;
    if (idx < NN) { offs[idx] = excl + local[i]; cursor[idx] = 0; }
  }
  if (t == 1023) offs[NN] = sums[1023];
}

__global__ void fill_kernel(const int* __restrict__ eidx, const int* __restrict__ offs,
                            int* __restrict__ cursor, int* __restrict__ sorted) {
  int e = blockIdx.x * 256 + threadIdx.x;
  if (e < NE) {
    int n = eidx[NE + e];
    int p = atomicAdd(&cursor[n], 1);
    sorted[offs[n] + p] = e;
  }
}

// wave per node: fp32 edge-state sums -> bf16 agg mirror (GEMM input rounding
// identical to previous f2bs-at-use; sum itself stays fp32)
__global__ void aggregate_kernel(const float* __restrict__ ef, const int* __restrict__ offs,
                                 const int* __restrict__ sorted, bf16* __restrict__ aggb) {
  const int node = blockIdx.x * 4 + (threadIdx.x >> 6);
  const int lane = threadIdx.x & 63;
  if (node >= NN) return;
  const int s = offs[node], t = offs[node + 1];
  float a0 = 0.f, a1 = 0.f;
  for (int i = s; i < t; i++) {
    const int e = sorted[i];
    a0 += ef[(size_t)e * DD + lane];
    a1 += ef[(size_t)e * DD + 64 + lane];
  }
  aggb[(size_t)node * DD + lane]      = (bf16)a0;
  aggb[(size_t)node * DD + 64 + lane] = (bf16)a1;
}

// ---------------------------------------------------------------------------
extern "C" void kernel_launch(void* const* d_in, const int* in_sizes, int n_in,
                              void* d_out, int out_size, void* d_ws, size_t ws_size,
                              hipStream_t stream) {
  const void* x_in = d_in[0];
  const void* e_in = d_in[1];
  const void* eW0 = d_in[2];
  const void* eB0 = d_in[3];
  const void* eW1 = d_in[4];
  const void* eB1 = d_in[5];
  const void* eW2 = d_in[6];
  const void* eB2 = d_in[7];
  const void* eG  = d_in[8];
  const void* eBt = d_in[9];
  const void* nW0 = d_in[10];
  const void* nB0 = d_in[11];
  const void* nW1 = d_in[12];
  const void* nB1 = d_in[13];
  const void* nW2 = d_in[14];
  const void* nB2 = d_in[15];
  const void* nG  = d_in[16];
  const void* nBt = d_in[17];
  const int*  eidx = (const int*)d_in[18];

  char* ws = (char*)d_ws;
  size_t off = 0;
  auto alloc = [&](size_t bytes) -> char* {
    char* p = ws + off;
    off = (off + bytes + 255) & ~(size_t)255;
    return p;
  };

  float* xf   = (float*)alloc((size_t)NN * DD * 4);   // fp32 residual states
  float* ef   = (float*)alloc((size_t)NE * DD * 4);
  bf16*  xb   = (bf16*)alloc((size_t)NN * DD * 2);    // bf16 mirrors (GEMM inputs)
  bf16*  eb   = (bf16*)alloc((size_t)NE * DD * 2);
  bf16*  aggb = (bf16*)alloc((size_t)NN * DD * 2);
  bf16*  eW0t = (bf16*)alloc((size_t)NITER * 384 * DD * 2);
  bf16*  eW1t = (bf16*)alloc((size_t)NITER * 128 * DD * 2);
  bf16*  eW2t = (bf16*)alloc((size_t)NITER * 128 * DD * 2);
  bf16*  nW0t = (bf16*)alloc((size_t)NITER * 256 * DD * 2);
  bf16*  nW1t = (bf16*)alloc((size_t)NITER * 128 * DD * 2);
  bf16*  nW2t = (bf16*)alloc((size_t)NITER * 128 * DD * 2);
  const int NB = NITER * DD;
  float* eB0f = (float*)alloc(NB * 4);
  float* eB1f = (float*)alloc(NB * 4);
  float* eB2f = (float*)alloc(NB * 4);
  float* eGf  = (float*)alloc(NB * 4);
  float* eBtf = (float*)alloc(NB * 4);
  float* nB0f = (float*)alloc(NB * 4);
  float* nB1f = (float*)alloc(NB * 4);
  float* nB2f = (float*)alloc(NB * 4);
  float* nGf  = (float*)alloc(NB * 4);
  float* nBtf = (float*)alloc(NB * 4);
  int* counts = (int*)alloc((size_t)NN * 4);
  int* cursor = (int*)alloc((size_t)NN * 4);
  int* offs   = (int*)alloc((size_t)(NN + 1) * 4);
  int* sorted = (int*)alloc((size_t)NE * 4);
  int* flag   = (int*)alloc(4);

  detect_kernel<<<1, 256, 0, stream>>>((const unsigned short*)x_in, 16384, flag);

  in2fb_kernel<<<(NN * DD + 255) / 256, 256, 0, stream>>>(x_in, xf, xb, NN * DD, flag);
  in2fb_kernel<<<(NE * DD + 255) / 256, 256, 0, stream>>>(e_in, ef, eb, NE * DD, flag);
  w2t_kernel<<<(NITER * 384 * DD + 255) / 256, 256, 0, stream>>>(eW0, eW0t, 384, flag);
  w2t_kernel<<<(NITER * 128 * DD + 255) / 256, 256, 0, stream>>>(eW1, eW1t, 128, flag);
  w2t_kernel<<<(NITER * 128 * DD + 255) / 256, 256, 0, stream>>>(eW2, eW2t, 128, flag);
  w2t_kernel<<<(NITER * 256 * DD + 255) / 256, 256, 0, stream>>>(nW0, nW0t, 256, flag);
  w2t_kernel<<<(NITER * 128 * DD + 255) / 256, 256, 0, stream>>>(nW1, nW1t, 128, flag);
  w2t_kernel<<<(NITER * 128 * DD + 255) / 256, 256, 0, stream>>>(nW2, nW2t, 128, flag);
  in2f_kernel<<<(NB + 255) / 256, 256, 0, stream>>>(eB0, eB0f, NB, flag);
  in2f_kernel<<<(NB + 255) / 256, 256, 0, stream>>>(eB1, eB1f, NB, flag);
  in2f_kernel<<<(NB + 255) / 256, 256, 0, stream>>>(eB2, eB2f, NB, flag);
  in2f_kernel<<<(NB + 255) / 256, 256, 0, stream>>>(eG,  eGf,  NB, flag);
  in2f_kernel<<<(NB + 255) / 256, 256, 0, stream>>>(eBt, eBtf, NB, flag);
  in2f_kernel<<<(NB + 255) / 256, 256, 0, stream>>>(nB0, nB0f, NB, flag);
  in2f_kernel<<<(NB + 255) / 256, 256, 0, stream>>>(nB1, nB1f, NB, flag);
  in2f_kernel<<<(NB + 255) / 256, 256, 0, stream>>>(nB2, nB2f, NB, flag);
  in2f_kernel<<<(NB + 255) / 256, 256, 0, stream>>>(nG,  nGf,  NB, flag);
  in2f_kernel<<<(NB + 255) / 256, 256, 0, stream>>>(nBt, nBtf, NB, flag);

  zero_kernel<<<(NN + 255) / 256, 256, 0, stream>>>(counts, NN);
  hist_kernel<<<(NE + 255) / 256, 256, 0, stream>>>(eidx, counts);
  scan_kernel<<<1, 1024, 0, stream>>>(counts, offs, cursor);
  fill_kernel<<<(NE + 255) / 256, 256, 0, stream>>>(eidx, offs, cursor, sorted);

  const int egrid = NE / 64;                // 1250
  const int ngrid = (NN + 63) / 64;         // 313

  for (int t = 0; t < NITER; t++) {
    fused_mlp<384, 1><<<egrid, 256, 0, stream>>>(
        xb, eb, eidx,
        eW0t + (size_t)t * 384 * DD, eW1t + (size_t)t * 128 * DD, eW2t + (size_t)t * 128 * DD,
        eB0f + t * DD, eB1f + t * DD, eB2f + t * DD,
        eGf + t * DD, eBtf + t * DD, ef, eb, NE);
    aggregate_kernel<<<(NN + 3) / 4, 256, 0, stream>>>(ef, offs, sorted, aggb);
    fused_mlp<256, 2><<<ngrid, 256, 0, stream>>>(
        xb, aggb, nullptr,
        nW0t + (size_t)t * 256 * DD, nW1t + (size_t)t * 128 * DD, nW2t + (size_t)t * 128 * DD,
        nB0f + t * DD, nB1f + t * DD, nB2f + t * DD,
        nGf + t * DD, nBtf + t * DD, xf, xb, NN);
  }

  outw_kernel<<<((NN + NE) * DD + 255) / 256, 256, 0, stream>>>(xf, ef, d_out, flag);
}

// Round 6
// 1293.601 us; speedup vs baseline: 1.7418x; 1.5176x over previous
//
#include <hip/hip_runtime.h>
#include <hip/hip_bf16.h>

typedef __hip_bfloat16 bf16;
typedef __attribute__((ext_vector_type(8))) short short8;
typedef __attribute__((ext_vector_type(4))) float f32x4;

#define NN 20000
#define NE 80000
#define DD 128
#define NITER 15
#define HSTRIDE 136   // 272 B row stride: 16B-aligned rows, 2-way LDS aliasing (free)

__device__ inline void gload16(const void* g, void* l) {
  __builtin_amdgcn_global_load_lds(
      (const __attribute__((address_space(1))) void*)g,
      (__attribute__((address_space(3))) void*)l, 16, 0, 0);
}

// ---------------------------------------------------------------------------
// dtype auto-detect. flag = 1 -> bf16 ; flag = 0 -> fp32.
// ---------------------------------------------------------------------------
__global__ void detect_kernel(const unsigned short* __restrict__ p, int nhalf,
                              int* __restrict__ flag) {
  __shared__ int cs[256], ct[256];
  const int t = threadIdx.x;
  int sane = 0, tot = 0;
  for (int i = 2 * t; i < nhalf; i += 512) {
    unsigned short v = p[i];
    int e = (v >> 7) & 0xFF;
    tot++;
    if (v == 0 || (e >= 80 && e <= 170)) sane++;
  }
  cs[t] = sane; ct[t] = tot;
  __syncthreads();
  for (int o = 128; o > 0; o >>= 1) {
    if (t < o) { cs[t] += cs[t + o]; ct[t] += ct[t + o]; }
    __syncthreads();
  }
  if (t == 0) *flag = (cs[0] * 10 > ct[0] * 7) ? 1 : 0;
}

__global__ void in2fb_kernel(const void* __restrict__ src, float* __restrict__ dstf,
                             bf16* __restrict__ dstb, int n, const int* __restrict__ flag) {
  int i = blockIdx.x * 256 + threadIdx.x;
  if (i < n) {
    float v = (*flag) ? (float)((const bf16*)src)[i] : ((const float*)src)[i];
    dstf[i] = v;
    dstb[i] = (bf16)v;
  }
}

__global__ void in2f_kernel(const void* __restrict__ src, float* __restrict__ dst,
                            int n, const int* __restrict__ flag) {
  int i = blockIdx.x * 256 + threadIdx.x;
  if (i < n) {
    dst[i] = (*flag) ? (float)((const bf16*)src)[i] : ((const float*)src)[i];
  }
}

// W [NITER][K][128] -> Wt [NITER][128][K] bf16
__global__ void w2t_kernel(const void* __restrict__ W, bf16* __restrict__ Wt,
                           int K, const int* __restrict__ flag) {
  int i = blockIdx.x * 256 + threadIdx.x;
  int total = NITER * K * DD;
  if (i < total) {
    float v = (*flag) ? (float)((const bf16*)W)[i] : ((const float*)W)[i];
    int t = i / (K * DD);
    int rem = i - t * K * DD;
    int k = rem >> 7;
    int n = rem & 127;
    Wt[(size_t)t * K * DD + (size_t)n * K + k] = (bf16)v;
  }
}

__global__ void outw_kernel(const float* __restrict__ xf, const float* __restrict__ ef,
                            void* __restrict__ out, const int* __restrict__ flag) {
  int i = blockIdx.x * 256 + threadIdx.x;
  const int nx = NN * DD, total = (NN + NE) * DD;
  if (i < total) {
    float v = (i < nx) ? xf[i] : ef[i - nx];
    if (*flag) ((bf16*)out)[i] = (bf16)v;
    else       ((float*)out)[i] = v;
  }
}

// ---------------------------------------------------------------------------
// Fused 3-layer MLP. 128-row x 128-col tile, 4 waves SPLIT BY ROWS (wave =
// 32 rows x 128 cols, acc 2x8). B-weights staged per 32-K slab into LDS via
// global_load_lds (8 KB DMA, read once per block, shared by all waves);
// A gathered direct-to-register. LayerNorm is LDS-free (full row per wave:
// 8 in-lane cols x 16-lane shuffle butterfly). Residual state fp32 + bf16
// mirror written in epilogue.
// AMODE 1: A0 = concat(xb[row[m]], xb[col[m]], eb[m])  (K0=384)
// AMODE 2: A0 = concat(xb[m], aggb[m])                 (K0=256)
// ---------------------------------------------------------------------------
template<int K0, int AMODE>
__global__ __launch_bounds__(256, 3) void fused_mlp(
    const bf16*  __restrict__ S0b,
    const bf16*  __restrict__ S1b,
    const int*   __restrict__ eidx,
    const bf16*  __restrict__ W0t,   // [128][K0]
    const bf16*  __restrict__ W1t,   // [128][128]
    const bf16*  __restrict__ W2t,   // [128][128]
    const float* __restrict__ b0,
    const float* __restrict__ b1,
    const float* __restrict__ b2,
    const float* __restrict__ gamma,
    const float* __restrict__ beta,
    float*       __restrict__ stf,   // fp32 residual state (in/out)
    bf16*        __restrict__ stb,   // bf16 mirror (out)
    int M)
{
  __shared__ __align__(16) bf16 Bls[128 * 32];       // one 32-K weight slab
  __shared__ __align__(16) bf16 Hls[128 * HSTRIDE];  // inter-layer activations

  const int tid  = threadIdx.x;
  const int lane = tid & 63;
  const int wv   = tid >> 6;                  // wave's 32-row band
  const int l15  = lane & 15, quad = lane >> 4;
  const int m0   = blockIdx.x * 128;

  const int scol = tid >> 2;                  // DMA: weight col 0..63 (+64)
  const int sk8  = (tid & 3) * 8;             // DMA: 8-elem chunk in slab

  int rowm[2], ir[2], ic[2];
#pragma unroll
  for (int mi = 0; mi < 2; mi++) {
    rowm[mi] = min(m0 + wv * 32 + mi * 16 + l15, M - 1);
    if (AMODE == 1) { ir[mi] = eidx[rowm[mi]]; ic[mi] = eidx[NE + rowm[mi]]; }
  }

  f32x4 acc[2][8];
#pragma unroll
  for (int i = 0; i < 2; i++)
#pragma unroll
    for (int j = 0; j < 8; j++) acc[i][j] = (f32x4){0.f, 0.f, 0.f, 0.f};

  // ---------------- Phase 1: H0 = relu(A0 @ W0 + b0) ----------------
#pragma unroll
  for (int s = 0; s < K0 / 32; s++) {
    const int kk = s * 32;
    __syncthreads();                                  // Bls free
    gload16(W0t + (size_t)scol * K0 + kk + sk8,        &Bls[scol * 32 + sk8]);
    gload16(W0t + (size_t)(scol + 64) * K0 + kk + sk8, &Bls[(scol + 64) * 32 + sk8]);
    short8 af[2];
    {
      const int ks = (kk & 127) + quad * 8;
#pragma unroll
      for (int mi = 0; mi < 2; mi++) {
        const bf16* base;
        if (AMODE == 1) {
          const int seg = kk >> 7;
          base = (seg == 0) ? S0b + (size_t)ir[mi] * DD
               : (seg == 1) ? S0b + (size_t)ic[mi] * DD
                            : S1b + (size_t)rowm[mi] * DD;
        } else {
          base = (kk >> 7) ? S1b + (size_t)rowm[mi] * DD
                           : S0b + (size_t)rowm[mi] * DD;
        }
        af[mi] = *(const short8*)(base + ks);
      }
    }
    __syncthreads();                                  // DMA + gathers complete
    short8 bfr[8];
#pragma unroll
    for (int ni = 0; ni < 8; ni++)
      bfr[ni] = *(const short8*)&Bls[(ni * 16 + l15) * 32 + quad * 8];
#pragma unroll
    for (int mi = 0; mi < 2; mi++)
#pragma unroll
      for (int ni = 0; ni < 8; ni++)
        acc[mi][ni] = __builtin_amdgcn_mfma_f32_16x16x32_bf16(af[mi], bfr[ni], acc[mi][ni], 0, 0, 0);
  }
  {
    float bv[8];
#pragma unroll
    for (int ni = 0; ni < 8; ni++) bv[ni] = b0[ni * 16 + l15];
#pragma unroll
    for (int mi = 0; mi < 2; mi++)
#pragma unroll
      for (int r = 0; r < 4; r++) {
        const int row = wv * 32 + mi * 16 + quad * 4 + r;
#pragma unroll
        for (int ni = 0; ni < 8; ni++)
          Hls[row * HSTRIDE + ni * 16 + l15] = (bf16)fmaxf(acc[mi][ni][r] + bv[ni], 0.f);
      }
  }

  // ---------------- Phase 2: H1 = relu(H0 @ W1 + b1) ----------------
#pragma unroll
  for (int i = 0; i < 2; i++)
#pragma unroll
    for (int j = 0; j < 8; j++) acc[i][j] = (f32x4){0.f, 0.f, 0.f, 0.f};
#pragma unroll
  for (int s = 0; s < 4; s++) {
    const int kk = s * 32;
    __syncthreads();                                  // Bls free (+ H0 visible)
    gload16(W1t + (size_t)scol * 128 + kk + sk8,        &Bls[scol * 32 + sk8]);
    gload16(W1t + (size_t)(scol + 64) * 128 + kk + sk8, &Bls[(scol + 64) * 32 + sk8]);
    __syncthreads();                                  // DMA complete
    short8 af[2], bfr[8];
#pragma unroll
    for (int mi = 0; mi < 2; mi++)
      af[mi] = *(const short8*)&Hls[(wv * 32 + mi * 16 + l15) * HSTRIDE + kk + quad * 8];
#pragma unroll
    for (int ni = 0; ni < 8; ni++)
      bfr[ni] = *(const short8*)&Bls[(ni * 16 + l15) * 32 + quad * 8];
#pragma unroll
    for (int mi = 0; mi < 2; mi++)
#pragma unroll
      for (int ni = 0; ni < 8; ni++)
        acc[mi][ni] = __builtin_amdgcn_mfma_f32_16x16x32_bf16(af[mi], bfr[ni], acc[mi][ni], 0, 0, 0);
  }
  __syncthreads();   // H0 reads done before overwrite (cheap insurance)
  {
    float bv[8];
#pragma unroll
    for (int ni = 0; ni < 8; ni++) bv[ni] = b1[ni * 16 + l15];
#pragma unroll
    for (int mi = 0; mi < 2; mi++)
#pragma unroll
      for (int r = 0; r < 4; r++) {
        const int row = wv * 32 + mi * 16 + quad * 4 + r;
#pragma unroll
        for (int ni = 0; ni < 8; ni++)
          Hls[row * HSTRIDE + ni * 16 + l15] = (bf16)fmaxf(acc[mi][ni][r] + bv[ni], 0.f);
      }
  }

  // ---------------- Phase 3: Y = H1 @ W2 + b2 ; LN ; residual ----------------
#pragma unroll
  for (int i = 0; i < 2; i++)
#pragma unroll
    for (int j = 0; j < 8; j++) acc[i][j] = (f32x4){0.f, 0.f, 0.f, 0.f};
#pragma unroll
  for (int s = 0; s < 4; s++) {
    const int kk = s * 32;
    __syncthreads();
    gload16(W2t + (size_t)scol * 128 + kk + sk8,        &Bls[scol * 32 + sk8]);
    gload16(W2t + (size_t)(scol + 64) * 128 + kk + sk8, &Bls[(scol + 64) * 32 + sk8]);
    __syncthreads();
    short8 af[2], bfr[8];
#pragma unroll
    for (int mi = 0; mi < 2; mi++)
      af[mi] = *(const short8*)&Hls[(wv * 32 + mi * 16 + l15) * HSTRIDE + kk + quad * 8];
#pragma unroll
    for (int ni = 0; ni < 8; ni++)
      bfr[ni] = *(const short8*)&Bls[(ni * 16 + l15) * 32 + quad * 8];
#pragma unroll
    for (int mi = 0; mi < 2; mi++)
#pragma unroll
      for (int ni = 0; ni < 8; ni++)
        acc[mi][ni] = __builtin_amdgcn_mfma_f32_16x16x32_bf16(af[mi], bfr[ni], acc[mi][ni], 0, 0, 0);
  }

  // LN: full row within wave -> in-lane ni-sum + 16-lane butterfly. No LDS.
  float bv[8], gv[8], btv[8];
#pragma unroll
  for (int ni = 0; ni < 8; ni++) {
    const int col = ni * 16 + l15;
    bv[ni] = b2[col]; gv[ni] = gamma[col]; btv[ni] = beta[col];
  }
#pragma unroll
  for (int mi = 0; mi < 2; mi++)
#pragma unroll
    for (int r = 0; r < 4; r++) {
      float a = 0.f, bq = 0.f;
#pragma unroll
      for (int ni = 0; ni < 8; ni++) {
        const float v = acc[mi][ni][r] + bv[ni];
        a += v; bq += v * v;
      }
#pragma unroll
      for (int off = 1; off < 16; off <<= 1) {
        a  += __shfl_xor(a, off);
        bq += __shfl_xor(bq, off);
      }
      const float mu = a * (1.0f / 128.0f);
      const float var = fmaxf(bq * (1.0f / 128.0f) - mu * mu, 0.0f);
      const float rs = rsqrtf(var + 1e-5f);
      const int m = m0 + wv * 32 + mi * 16 + quad * 4 + r;
      if (m < M) {
#pragma unroll
        for (int ni = 0; ni < 8; ni++) {
          const int col = ni * 16 + l15;
          const float v = acc[mi][ni][r] + bv[ni];
          const float lnv = (v - mu) * rs * gv[ni] + btv[ni];
          const size_t idx = (size_t)m * DD + col;
          const float nv = lnv + stf[idx];
          stf[idx] = nv;
          stb[idx] = (bf16)nv;
        }
      }
    }
}

// --------------------------- CSR build + aggregate -------------------------
__global__ void zero_kernel(int* __restrict__ p, int n) {
  int i = blockIdx.x * 256 + threadIdx.x;
  if (i < n) p[i] = 0;
}

__global__ void hist_kernel(const int* __restrict__ eidx, int* __restrict__ counts) {
  int e = blockIdx.x * 256 + threadIdx.x;
  if (e < NE) atomicAdd(&counts[eidx[NE + e]], 1);
}

__global__ void scan_kernel(const int* __restrict__ counts, int* __restrict__ offs,
                            int* __restrict__ cursor) {
  __shared__ int sums[1024];
  const int t = threadIdx.x;
  const int base = t * 20;
  int local[20];
  int s = 0;
  for (int i = 0; i < 20; i++) {
    int idx = base + i;
    int c = (idx < NN) ? counts[idx] : 0;
    local[i] = s; s += c;
  }
  sums[t] = s;
  __syncthreads();
  for (int off = 1; off < 1024; off <<= 1) {
    int v = 0;
    if (t >= off) v = sums[t - off];
    __syncthreads();
    if (t >= off) sums[t] += v;
    __syncthreads();
  }
  int excl = (t == 0) ? 0 : sums[t - 1];
  for (int i = 0; i < 20; i++) {
    int idx = base + i;
    if (idx < NN) { offs[idx] = excl + local[i]; cursor[idx] = 0; }
  }
  if (t == 1023) offs[NN] = sums[1023];
}

__global__ void fill_kernel(const int* __restrict__ eidx, const int* __restrict__ offs,
                            int* __restrict__ cursor, int* __restrict__ sorted) {
  int e = blockIdx.x * 256 + threadIdx.x;
  if (e < NE) {
    int n = eidx[NE + e];
    int p = atomicAdd(&cursor[n], 1);
    sorted[offs[n] + p] = e;
  }
}

// wave per node: sum bf16 edge mirrors in fp32 -> bf16 agg
__global__ void aggregate_kernel(const bf16* __restrict__ eb, const int* __restrict__ offs,
                                 const int* __restrict__ sorted, bf16* __restrict__ aggb) {
  const int node = blockIdx.x * 4 + (threadIdx.x >> 6);
  const int lane = threadIdx.x & 63;
  if (node >= NN) return;
  const int s = offs[node], t = offs[node + 1];
  float a0 = 0.f, a1 = 0.f;
  for (int i = s; i < t; i++) {
    const int e = sorted[i];
    a0 += (float)eb[(size_t)e * DD + lane];
    a1 += (float)eb[(size_t)e * DD + 64 + lane];
  }
  aggb[(size_t)node * DD + lane]      = (bf16)a0;
  aggb[(size_t)node * DD + 64 + lane] = (bf16)a1;
}

// ---------------------------------------------------------------------------
extern "C" void kernel_launch(void* const* d_in, const int* in_sizes, int n_in,
                              void* d_out, int out_size, void* d_ws, size_t ws_size,
                              hipStream_t stream) {
  const void* x_in = d_in[0];
  const void* e_in = d_in[1];
  const void* eW0 = d_in[2];
  const void* eB0 = d_in[3];
  const void* eW1 = d_in[4];
  const void* eB1 = d_in[5];
  const void* eW2 = d_in[6];
  const void* eB2 = d_in[7];
  const void* eG  = d_in[8];
  const void* eBt = d_in[9];
  const void* nW0 = d_in[10];
  const void* nB0 = d_in[11];
  const void* nW1 = d_in[12];
  const void* nB1 = d_in[13];
  const void* nW2 = d_in[14];
  const void* nB2 = d_in[15];
  const void* nG  = d_in[16];
  const void* nBt = d_in[17];
  const int*  eidx = (const int*)d_in[18];

  char* ws = (char*)d_ws;
  size_t off = 0;
  auto alloc = [&](size_t bytes) -> char* {
    char* p = ws + off;
    off = (off + bytes + 255) & ~(size_t)255;
    return p;
  };

  float* xf   = (float*)alloc((size_t)NN * DD * 4);   // fp32 residual states
  float* ef   = (float*)alloc((size_t)NE * DD * 4);
  bf16*  xb   = (bf16*)alloc((size_t)NN * DD * 2);    // bf16 mirrors (GEMM inputs)
  bf16*  eb   = (bf16*)alloc((size_t)NE * DD * 2);
  bf16*  aggb = (bf16*)alloc((size_t)NN * DD * 2);
  bf16*  eW0t = (bf16*)alloc((size_t)NITER * 384 * DD * 2);
  bf16*  eW1t = (bf16*)alloc((size_t)NITER * 128 * DD * 2);
  bf16*  eW2t = (bf16*)alloc((size_t)NITER * 128 * DD * 2);
  bf16*  nW0t = (bf16*)alloc((size_t)NITER * 256 * DD * 2);
  bf16*  nW1t = (bf16*)alloc((size_t)NITER * 128 * DD * 2);
  bf16*  nW2t = (bf16*)alloc((size_t)NITER * 128 * DD * 2);
  const int NB = NITER * DD;
  float* eB0f = (float*)alloc(NB * 4);
  float* eB1f = (float*)alloc(NB * 4);
  float* eB2f = (float*)alloc(NB * 4);
  float* eGf  = (float*)alloc(NB * 4);
  float* eBtf = (float*)alloc(NB * 4);
  float* nB0f = (float*)alloc(NB * 4);
  float* nB1f = (float*)alloc(NB * 4);
  float* nB2f = (float*)alloc(NB * 4);
  float* nGf  = (float*)alloc(NB * 4);
  float* nBtf = (float*)alloc(NB * 4);
  int* counts = (int*)alloc((size_t)NN * 4);
  int* cursor = (int*)alloc((size_t)NN * 4);
  int* offs   = (int*)alloc((size_t)(NN + 1) * 4);
  int* sorted = (int*)alloc((size_t)NE * 4);
  int* flag   = (int*)alloc(4);

  detect_kernel<<<1, 256, 0, stream>>>((const unsigned short*)x_in, 16384, flag);

  in2fb_kernel<<<(NN * DD + 255) / 256, 256, 0, stream>>>(x_in, xf, xb, NN * DD, flag);
  in2fb_kernel<<<(NE * DD + 255) / 256, 256, 0, stream>>>(e_in, ef, eb, NE * DD, flag);
  w2t_kernel<<<(NITER * 384 * DD + 255) / 256, 256, 0, stream>>>(eW0, eW0t, 384, flag);
  w2t_kernel<<<(NITER * 128 * DD + 255) / 256, 256, 0, stream>>>(eW1, eW1t, 128, flag);
  w2t_kernel<<<(NITER * 128 * DD + 255) / 256, 256, 0, stream>>>(eW2, eW2t, 128, flag);
  w2t_kernel<<<(NITER * 256 * DD + 255) / 256, 256, 0, stream>>>(nW0, nW0t, 256, flag);
  w2t_kernel<<<(NITER * 128 * DD + 255) / 256, 256, 0, stream>>>(nW1, nW1t, 128, flag);
  w2t_kernel<<<(NITER * 128 * DD + 255) / 256, 256, 0, stream>>>(nW2, nW2t, 128, flag);
  in2f_kernel<<<(NB + 255) / 256, 256, 0, stream>>>(eB0, eB0f, NB, flag);
  in2f_kernel<<<(NB + 255) / 256, 256, 0, stream>>>(eB1, eB1f, NB, flag);
  in2f_kernel<<<(NB + 255) / 256, 256, 0, stream>>>(eB2, eB2f, NB, flag);
  in2f_kernel<<<(NB + 255) / 256, 256, 0, stream>>>(eG,  eGf,  NB, flag);
  in2f_kernel<<<(NB + 255) / 256, 256, 0, stream>>>(eBt, eBtf, NB, flag);
  in2f_kernel<<<(NB + 255) / 256, 256, 0, stream>>>(nB0, nB0f, NB, flag);
  in2f_kernel<<<(NB + 255) / 256, 256, 0, stream>>>(nB1, nB1f, NB, flag);
  in2f_kernel<<<(NB + 255) / 256, 256, 0, stream>>>(nB2, nB2f, NB, flag);
  in2f_kernel<<<(NB + 255) / 256, 256, 0, stream>>>(nG,  nGf,  NB, flag);
  in2f_kernel<<<(NB + 255) / 256, 256, 0, stream>>>(nBt, nBtf, NB, flag);

  zero_kernel<<<(NN + 255) / 256, 256, 0, stream>>>(counts, NN);
  hist_kernel<<<(NE + 255) / 256, 256, 0, stream>>>(eidx, counts);
  scan_kernel<<<1, 1024, 0, stream>>>(counts, offs, cursor);
  fill_kernel<<<(NE + 255) / 256, 256, 0, stream>>>(eidx, offs, cursor, sorted);

  const int egrid = NE / 128;               // 625 (all co-resident at 3 blk/CU)
  const int ngrid = (NN + 127) / 128;       // 157

  for (int t = 0; t < NITER; t++) {
    fused_mlp<384, 1><<<egrid, 256, 0, stream>>>(
        xb, eb, eidx,
        eW0t + (size_t)t * 384 * DD, eW1t + (size_t)t * 128 * DD, eW2t + (size_t)t * 128 * DD,
        eB0f + t * DD, eB1f + t * DD, eB2f + t * DD,
        eGf + t * DD, eBtf + t * DD, ef, eb, NE);
    aggregate_kernel<<<(NN + 3) / 4, 256, 0, stream>>>(eb, offs, sorted, aggb);
    fused_mlp<256, 2><<<ngrid, 256, 0, stream>>>(
        xb, aggb, nullptr,
        nW0t + (size_t)t * 256 * DD, nW1t + (size_t)t * 128 * DD, nW2t + (size_t)t * 128 * DD,
        nB0f + t * DD, nB1f + t * DD, nB2f + t * DD,
        nGf + t * DD, nBtf + t * DD, xf, xb, NN);
  }

  outw_kernel<<<((NN + NE) * DD + 255) / 256, 256, 0, stream>>>(xf, ef, d_out, flag);
}